// Round 19
// baseline (316.907 us; speedup 1.0000x reference)
//
#include <hip/hip_runtime.h>
#include <math.h>

#define N_NODES 50000
#define N_EDGES 800000
#define IN_DIM 128
#define HID 256
#define NCLASS 40

#define SCAN_NBLK 49   // ceil(50000 / 1024)
#define CPAD 16        // cursor padded to one int per 64B line

typedef __attribute__((ext_vector_type(8))) short short8;
typedef __attribute__((ext_vector_type(4))) float floatx4;

// ---------- bf16 helpers (RNE pack, cheap unpack) ----------
__device__ inline unsigned bf16pair(float a, float b) {
    unsigned ua = __float_as_uint(a), ub = __float_as_uint(b);
    ua = (ua + 0x7fffu + ((ua >> 16) & 1u)) >> 16;
    ub = (ub + 0x7fffu + ((ub >> 16) & 1u)) >> 16;
    return ua | (ub << 16);
}
__device__ inline unsigned bf16bits(float a) {
    unsigned ua = __float_as_uint(a);
    return (ua + 0x7fffu + ((ua >> 16) & 1u)) >> 16;
}
__device__ inline float bf_lo(unsigned u) { return __uint_as_float(u << 16); }
__device__ inline float bf_hi(unsigned u) { return __uint_as_float(u & 0xffff0000u); }

// ---------------- prep: feats->bf16, edge count, W1 fragment pack (fused) ----------------
__global__ void prep_kernel(const float4* __restrict__ f4,
                            uint2* __restrict__ fb16,
                            const int* __restrict__ rows,
                            int* __restrict__ counts,
                            const float* __restrict__ W1,
                            uint4* __restrict__ W1frag) {
    int i = blockIdx.x * blockDim.x + threadIdx.x;   // < 1.6M
    float4 v = f4[i];
    fb16[i] = make_uint2(bf16pair(v.x, v.y), bf16pair(v.z, v.w));
    if (i < N_EDGES) atomicAdd(&counts[rows[i]], 1);
    if (i < 4096) {
        int f = i;
        int h = f >> 11, rem = f & 2047;
        int t = rem >> 8, s = (rem >> 6) & 3, l = rem & 63;
        int q = l >> 4, n16 = l & 15;
        int n = h * 128 + t * 16 + n16;
        int kb = s * 32 + q * 8;
        unsigned p[4];
        #pragma unroll
        for (int jj = 0; jj < 4; ++jj) {
            float a = W1[(size_t)(kb + 2 * jj) * HID + n];
            float b = W1[(size_t)(kb + 2 * jj + 1) * HID + n];
            p[jj] = bf16pair(a, b);
        }
        W1frag[f] = make_uint4(p[0], p[1], p[2], p[3]);
    }
}

// ---------------- hierarchical scan, phase 1: per-block sums ----------------
__global__ void block_sum_kernel(const int* __restrict__ counts,
                                 int* __restrict__ blockSums) {
    int t = threadIdx.x;
    int base = blockIdx.x * 1024 + t * 4;
    int s = 0;
    if (base < N_NODES) {
        int4 c = *(const int4*)(counts + base);
        s = c.x + c.y + c.z + c.w;
    }
    #pragma unroll
    for (int off = 32; off >= 1; off >>= 1)
        s += __shfl_xor(s, off);
    __shared__ int wsum[4];
    int lane = t & 63, wid = t >> 6;
    if (lane == 0) wsum[wid] = s;
    __syncthreads();
    if (t == 0)
        blockSums[blockIdx.x] = wsum[0] + wsum[1] + wsum[2] + wsum[3];
}

// ---------------- phase 2: scan the 49 block sums (single wave) ----------------
__global__ void block_offset_kernel(const int* __restrict__ blockSums,
                                    int* __restrict__ blockOffs,
                                    int* __restrict__ row_start) {
    int lane = threadIdx.x;          // 64 threads
    int x = (lane < SCAN_NBLK) ? blockSums[lane] : 0;
    #pragma unroll
    for (int off = 1; off < 64; off <<= 1) {
        int y = __shfl_up(x, off);
        if (lane >= off) x += y;
    }
    int excl = __shfl_up(x, 1);
    if (lane == 0) excl = 0;
    if (lane < SCAN_NBLK) blockOffs[lane] = excl;
    if (lane == SCAN_NBLK - 1) row_start[N_NODES] = x;   // grand total
}

// ---------------- phase 3: local scan -> row_start (compact), cursor (padded) ----------------
__global__ void local_scan_kernel(const int* __restrict__ counts,
                                  const int* __restrict__ blockOffs,
                                  int* __restrict__ row_start,
                                  int* __restrict__ cursor) {
    int t = threadIdx.x;
    int base = blockIdx.x * 1024 + t * 4;
    int4 c = make_int4(0, 0, 0, 0);
    if (base < N_NODES) c = *(const int4*)(counts + base);
    int s0 = c.x, s1 = s0 + c.y, s2 = s1 + c.z, s3 = s2 + c.w;
    int tsum = s3;
    int lane = t & 63, wid = t >> 6;
    int x = tsum;
    #pragma unroll
    for (int off = 1; off < 64; off <<= 1) {
        int y = __shfl_up(x, off);
        if (lane >= off) x += y;
    }
    __shared__ int wsum[4];
    if (lane == 63) wsum[wid] = x;
    __syncthreads();
    int woff = 0;
    for (int i = 0; i < 4; ++i)
        if (i < wid) woff += wsum[i];
    int excl = x - tsum + woff + blockOffs[blockIdx.x];
    if (base < N_NODES) {
        int4 rs = make_int4(excl, excl + s0, excl + s1, excl + s2);
        *(int4*)(row_start + base) = rs;
        cursor[(size_t)(base + 0) * CPAD] = rs.x;
        cursor[(size_t)(base + 1) * CPAD] = rs.y;
        cursor[(size_t)(base + 2) * CPAD] = rs.z;
        cursor[(size_t)(base + 3) * CPAD] = rs.w;
    }
}

// ---------------- scatter: 8 edges/thread (independent atomic->store chains) ----------------
__global__ void scatter_kernel(const int* __restrict__ rows,
                               const int* __restrict__ cols,
                               const float* __restrict__ vals,
                               int* __restrict__ cursor,
                               unsigned* __restrict__ csr_cv) {
    int base = blockIdx.x * 2048 + threadIdx.x;
    int e[8], r[8]; unsigned pk[8];
    #pragma unroll
    for (int k = 0; k < 8; ++k) {
        e[k] = base + k * 256;
        if (e[k] < N_EDGES) {
            r[k] = rows[e[k]];
            pk[k] = ((unsigned)cols[e[k]] << 16) | bf16bits(vals[e[k]]);
        }
    }
    int pos[8];
    #pragma unroll
    for (int k = 0; k < 8; ++k)
        if (e[k] < N_EDGES)
            pos[k] = atomicAdd(&cursor[(size_t)r[k] * CPAD], 1);
    #pragma unroll
    for (int k = 0; k < 8; ++k)
        if (e[k] < N_EDGES)
            csr_cv[pos[k]] = pk[k];
}

// ---------------- SpMM (CSR, quarter-wave per edge, 16-edge unrolled gathers) ----------------
// lane = 16p+q: p = edge-of-quad, q = dim group of 8 (one uint4 of Hin row).
// Inner step handles 16 edges (4 quads): four independent shuffle->gather chains
// in flight. Mean degree = 16, so a typical row finishes in ONE iteration.
// val=0 padding beyond cnt makes over-run safe; max src lane = 48+12+3 = 63.
// MODE 0: Hout_b[r] = bf16(acc)                              (hop 2)
// MODE 1: Hout_b[r] = bf16(0.5*acc)                          (hop 1, folds input scale)
// MODE 2: Hout_b[r] = bf16(0.5*feats[r] + h1[r] + h2[r] + acc)  (hop 3, y in bf16)
template <int MODE>
__global__ void spmm_csr(const int* __restrict__ row_start,
                         const unsigned* __restrict__ csr_cv,
                         const uint4* __restrict__ Hin4,
                         uint4* __restrict__ Hout4,
                         const float* __restrict__ feats,
                         const uint4* __restrict__ h1b4,
                         const uint4* __restrict__ h2b4) {
    int wave = (blockIdx.x * blockDim.x + threadIdx.x) >> 6;
    int lane = threadIdx.x & 63;
    if (wave >= N_NODES) return;
    int p = lane >> 4;          // 0..3: which edge of the quad
    int q = lane & 15;          // dim group (8 dims = one uint4)
    int start = row_start[wave];
    int end   = row_start[wave + 1];
    float acc[8] = {};
    for (int base = start; base < end; base += 64) {
        int idx = base + lane;
        unsigned u = 0;                         // col=0, val=+0.0
        if (idx < end) u = csr_cv[idx];
        int cnt = min(64, end - base);
        for (int j = 0; j < cnt; j += 16) {
            unsigned uj0 = __shfl(u, j + p);
            unsigned uj1 = __shfl(u, j + 4 + p);
            unsigned uj2 = __shfl(u, j + 8 + p);
            unsigned uj3 = __shfl(u, j + 12 + p);
            int   c0 = uj0 >> 16, c1 = uj1 >> 16, c2 = uj2 >> 16, c3 = uj3 >> 16;
            float v0 = __uint_as_float(uj0 << 16);
            float v1 = __uint_as_float(uj1 << 16);
            float v2 = __uint_as_float(uj2 << 16);
            float v3 = __uint_as_float(uj3 << 16);
            uint4 h0 = Hin4[(size_t)c0 * 16 + q];   // 4 independent gathers
            uint4 h1 = Hin4[(size_t)c1 * 16 + q];
            uint4 h2 = Hin4[(size_t)c2 * 16 + q];
            uint4 h3 = Hin4[(size_t)c3 * 16 + q];
            acc[0] += v0 * bf_lo(h0.x); acc[1] += v0 * bf_hi(h0.x);
            acc[2] += v0 * bf_lo(h0.y); acc[3] += v0 * bf_hi(h0.y);
            acc[4] += v0 * bf_lo(h0.z); acc[5] += v0 * bf_hi(h0.z);
            acc[6] += v0 * bf_lo(h0.w); acc[7] += v0 * bf_hi(h0.w);
            acc[0] += v1 * bf_lo(h1.x); acc[1] += v1 * bf_hi(h1.x);
            acc[2] += v1 * bf_lo(h1.y); acc[3] += v1 * bf_hi(h1.y);
            acc[4] += v1 * bf_lo(h1.z); acc[5] += v1 * bf_hi(h1.z);
            acc[6] += v1 * bf_lo(h1.w); acc[7] += v1 * bf_hi(h1.w);
            acc[0] += v2 * bf_lo(h2.x); acc[1] += v2 * bf_hi(h2.x);
            acc[2] += v2 * bf_lo(h2.y); acc[3] += v2 * bf_hi(h2.y);
            acc[4] += v2 * bf_lo(h2.z); acc[5] += v2 * bf_hi(h2.z);
            acc[6] += v2 * bf_lo(h2.w); acc[7] += v2 * bf_hi(h2.w);
            acc[0] += v3 * bf_lo(h3.x); acc[1] += v3 * bf_hi(h3.x);
            acc[2] += v3 * bf_lo(h3.y); acc[3] += v3 * bf_hi(h3.y);
            acc[4] += v3 * bf_lo(h3.z); acc[5] += v3 * bf_hi(h3.z);
            acc[6] += v3 * bf_lo(h3.w); acc[7] += v3 * bf_hi(h3.w);
        }
    }
    // reduce the 4 edge-subsets (lanes differing in bits 4..5)
    #pragma unroll
    for (int i = 0; i < 8; ++i) {
        acc[i] += __shfl_xor(acc[i], 16);
        acc[i] += __shfl_xor(acc[i], 32);
    }
    if (p == 0) {
        size_t o16 = (size_t)wave * 16 + q;
        if (MODE == 1) {
            #pragma unroll
            for (int i = 0; i < 8; ++i) acc[i] *= 0.5f;
        } else if (MODE == 2) {
            size_t of = (size_t)wave * IN_DIM + q * 8;
            float4 f0 = *(const float4*)(feats + of);
            float4 f1 = *(const float4*)(feats + of + 4);
            uint4 a = h1b4[o16];
            uint4 b = h2b4[o16];
            acc[0] += 0.5f * f0.x + bf_lo(a.x) + bf_lo(b.x);
            acc[1] += 0.5f * f0.y + bf_hi(a.x) + bf_hi(b.x);
            acc[2] += 0.5f * f0.z + bf_lo(a.y) + bf_lo(b.y);
            acc[3] += 0.5f * f0.w + bf_hi(a.y) + bf_hi(b.y);
            acc[4] += 0.5f * f1.x + bf_lo(a.z) + bf_lo(b.z);
            acc[5] += 0.5f * f1.y + bf_hi(a.z) + bf_hi(b.z);
            acc[6] += 0.5f * f1.z + bf_lo(a.w) + bf_lo(b.w);
            acc[7] += 0.5f * f1.w + bf_hi(a.w) + bf_hi(b.w);
        }
        Hout4[o16] = make_uint4(bf16pair(acc[0], acc[1]), bf16pair(acc[2], acc[3]),
                                bf16pair(acc[4], acc[5]), bf16pair(acc[6], acc[7]));
    }
}

// ---------------- GEMM1 (MFMA): H1 = relu(0.25*(ybf16 @ W1) + b1) ----------------
__global__ void gemm1_mfma(const uint4* __restrict__ yb4,
                           const uint4* __restrict__ W1frag,
                           const float* __restrict__ bias1,
                           float* __restrict__ H1) {
    __shared__ uint4 wlds[2048];   // 32 KB: this block's N-half of W1 fragments
    int tid = threadIdx.x;
    int h = blockIdx.y;
    for (int i = tid; i < 2048; i += 256)
        wlds[i] = W1frag[h * 2048 + i];
    __syncthreads();

    int wave = tid >> 6, lane = tid & 63;
    int q = lane >> 4, c16 = lane & 15;
    int row0 = blockIdx.x * 64 + wave * 16;
    int arow = row0 + c16;

    union { uint4 u; short8 v; } au[4], bu;
    if (arow < N_NODES) {
        #pragma unroll
        for (int s = 0; s < 4; ++s)
            au[s].u = yb4[(size_t)arow * 16 + 4 * s + q];
    } else {
        #pragma unroll
        for (int s = 0; s < 4; ++s)
            au[s].u = make_uint4(0u, 0u, 0u, 0u);
    }

    #pragma unroll
    for (int t = 0; t < 8; ++t) {
        floatx4 acc = {0.f, 0.f, 0.f, 0.f};
        #pragma unroll
        for (int s = 0; s < 4; ++s) {
            bu.u = wlds[(t * 4 + s) * 64 + lane];
            acc = __builtin_amdgcn_mfma_f32_16x16x32_bf16(au[s].v, bu.v, acc, 0, 0, 0);
        }
        int col = h * 128 + t * 16 + c16;
        float bs = bias1[col];
        #pragma unroll
        for (int r = 0; r < 4; ++r) {
            int crow = row0 + q * 4 + r;
            if (crow < N_NODES) {
                float v = 0.25f * acc[r] + bs;
                H1[(size_t)crow * HID + col] = v > 0.f ? v : 0.f;
            }
        }
    }
}

// ---------------- GEMM2 (K-split x2): partial = H1[:, khalf] @ W2[khalf, :] ----------------
#define G2_BM 128
#define G2_BK 32
__global__ void gemm2_kernel(const float* __restrict__ H1,
                             const float* __restrict__ W2,
                             float* __restrict__ part0,
                             float* __restrict__ part1) {
    __shared__ float As[G2_BK][G2_BM + 4];   // transposed A
    __shared__ float Bs[G2_BK][44];          // 32 x 40, row pad to 44
    int tid = threadIdx.x;                   // 256
    int rt = tid >> 3;                       // 0..31, 4 rows each
    int ct = tid & 7;                        // 0..7, 5 cols each
    int row0 = blockIdx.x * G2_BM;
    int kbase = blockIdx.y * (HID / 2);      // 0 or 128
    float* outp = blockIdx.y ? part1 : part0;
    float acc[4][5] = {};
    for (int kt = 0; kt < HID / 2; kt += G2_BK) {    // 4 k-tiles
        int k0 = kbase + kt;
        #pragma unroll
        for (int i = tid; i < 1024; i += 256) {
            int r = i >> 3, u = i & 7;
            int gr = row0 + r;
            float4 v = make_float4(0.f, 0.f, 0.f, 0.f);
            if (gr < N_NODES)
                v = *(const float4*)(H1 + (size_t)gr * HID + k0 + u * 4);
            int kb = u * 4;
            As[kb + 0][r] = v.x;
            As[kb + 1][r] = v.y;
            As[kb + 2][r] = v.z;
            As[kb + 3][r] = v.w;
        }
        for (int i = tid; i < 320; i += 256) {
            int r = i / 10, cg = i % 10;
            float4 w = *(const float4*)(W2 + (size_t)(k0 + r) * NCLASS + cg * 4);
            *(float4*)&Bs[r][cg * 4] = w;
        }
        __syncthreads();
        #pragma unroll
        for (int kk = 0; kk < G2_BK; ++kk) {
            float4 a0 = *(const float4*)&As[kk][rt * 4];
            float a[4] = {a0.x, a0.y, a0.z, a0.w};
            float b[5];
            #pragma unroll
            for (int j = 0; j < 5; ++j) b[j] = Bs[kk][ct * 5 + j];
            #pragma unroll
            for (int i = 0; i < 4; ++i)
                #pragma unroll
                for (int j = 0; j < 5; ++j)
                    acc[i][j] += a[i] * b[j];
        }
        __syncthreads();
    }
    #pragma unroll
    for (int i = 0; i < 4; ++i) {
        int gr = row0 + rt * 4 + i;
        if (gr >= N_NODES) continue;
        float* dst = outp + (size_t)gr * NCLASS + ct * 5;
        #pragma unroll
        for (int j = 0; j < 5; ++j)
            dst[j] = acc[i][j];
    }
}

// ---------------- double log_softmax (sums K-split partials + bias) ----------------
__global__ void lsm_kernel(const float* __restrict__ part0,
                           const float* __restrict__ part1,
                           const float* __restrict__ b2,
                           float* __restrict__ Out) {
    int wave = threadIdx.x >> 6;
    int lane = threadIdx.x & 63;
    int row = blockIdx.x * 4 + wave;
    if (row >= N_NODES) return;

    float acc = -INFINITY;
    if (lane < NCLASS) {
        size_t idx = (size_t)row * NCLASS + lane;
        acc = part0[idx] + part1[idx] + b2[lane];
    }

    float m = acc;
    #pragma unroll
    for (int off = 32; off >= 1; off >>= 1)
        m = fmaxf(m, __shfl_xor(m, off));
    float ex = (lane < NCLASS) ? expf(acc - m) : 0.f;
    float s = ex;
    #pragma unroll
    for (int off = 32; off >= 1; off >>= 1)
        s += __shfl_xor(s, off);
    float z1 = acc - (m + logf(s));

    float m2 = z1;
    #pragma unroll
    for (int off = 32; off >= 1; off >>= 1)
        m2 = fmaxf(m2, __shfl_xor(m2, off));
    float ex2 = (lane < NCLASS) ? expf(z1 - m2) : 0.f;
    float s2 = ex2;
    #pragma unroll
    for (int off = 32; off >= 1; off >>= 1)
        s2 += __shfl_xor(s2, off);
    float z2 = z1 - (m2 + logf(s2));

    if (lane < NCLASS)
        Out[(size_t)row * NCLASS + lane] = z2;
}

extern "C" void kernel_launch(void* const* d_in, const int* in_sizes, int n_in,
                              void* d_out, int out_size, void* d_ws, size_t ws_size,
                              hipStream_t stream) {
    const float* feats   = (const float*)d_in[0];
    const int*   e_row   = (const int*)d_in[1];
    const int*   e_col   = (const int*)d_in[2];
    const float* e_vals  = (const float*)d_in[3];
    const float* W1      = (const float*)d_in[4];
    const float* b1      = (const float*)d_in[5];
    const float* W2      = (const float*)d_in[6];
    const float* b2      = (const float*)d_in[7];
    float* out = (float*)d_out;

    // Workspace layout (19.2M floats):
    //   ybf   : [0, 3.2M)           y in bf16 (MLP input, written by hop3)
    //   W1frag: [3.2M, 3.216M)      W1 bf16 MFMA fragments (64 KB)
    //   fb16  : [6.4M, 9.6M)        feats in bf16
    //   h1b   : [9.6M, 12.8M)       hop1 out, bf16
    //   h2b   : [12.8M, 16M)        hop2 out, bf16
    //   counts: [16M, 16.05M)       compact counters (dead after scan)
    //   cursor: [16.8M, 17.6M)      line-padded cursors (dead after scatter)
    //   hid   : [6.4M, 19.2M)       gemm1 out fp32 (all above dead by then)
    //   part0 : [0, 2M)  part1: [2M, 4M)
    float* ws    = (float*)d_ws;
    uint4* ybf4  = (uint4*)ws;
    uint4* W1frag = (uint4*)(ws + (size_t)N_NODES * IN_DIM / 2);
    uint4* fb16_4 = (uint4*)(ws + (size_t)N_NODES * IN_DIM);
    uint4* h1b4  = (uint4*)(ws + (size_t)N_NODES * IN_DIM * 3 / 2);
    uint4* h2b4  = (uint4*)(ws + (size_t)N_NODES * IN_DIM * 2);
    int*   counts = (int*)(ws + (size_t)N_NODES * IN_DIM * 5 / 2);   // 16M
    int*   cursor = counts + 800000;                                 // 16.8M
    float* hid   = ws + (size_t)N_NODES * IN_DIM;
    float* part0 = ws;
    float* part1 = ws + (size_t)N_NODES * NCLASS;

    // CSR scratch in d_out (8 MB; fully overwritten by lsm_kernel at the end).
    unsigned* csr_cv = (unsigned*)d_out;                 // packed (col<<16)|bf16(val), 800000
    int*   row_start = (int*)d_out + 2 * N_EDGES;        // [1600000, 1650001)
    int*   blockSums = row_start + N_NODES + 4;
    int*   blockOffs = blockSums + 64;                   // < 2000000

    // zero compact counts (200 KB)
    hipMemsetAsync(counts, 0, N_NODES * sizeof(int), stream);

    // prep: feats->bf16 + edge count + W1 fragment pack
    const int ELEMS4 = N_NODES * IN_DIM / 4;  // 1.6M float4s
    prep_kernel<<<ELEMS4 / 256, 256, 0, stream>>>((const float4*)feats, (uint2*)fb16_4,
                                                  e_row, counts, W1, W1frag);

    // Hierarchical scan -> row_start (compact) + cursor (padded)
    block_sum_kernel<<<SCAN_NBLK, 256, 0, stream>>>(counts, blockSums);
    block_offset_kernel<<<1, 64, 0, stream>>>(blockSums, blockOffs, row_start);
    local_scan_kernel<<<SCAN_NBLK, 256, 0, stream>>>(counts, blockOffs, row_start, cursor);

    // scatter: 8 edges per thread
    scatter_kernel<<<(N_EDGES + 2047) / 2048, 256, 0, stream>>>(e_row, e_col, e_vals,
                                                                cursor, csr_cv);

    // 3 propagation hops (quarter-wave per edge, 16-edge unrolled; hop3 emits bf16 y)
    const int SPMM_BLOCKS = N_NODES / 4;      // 12500 (4 waves/block)
    spmm_csr<1><<<SPMM_BLOCKS, 256, 0, stream>>>(row_start, csr_cv, fb16_4, h1b4,
                                                 nullptr, nullptr, nullptr);
    spmm_csr<0><<<SPMM_BLOCKS, 256, 0, stream>>>(row_start, csr_cv, h1b4, h2b4,
                                                 nullptr, nullptr, nullptr);
    spmm_csr<2><<<SPMM_BLOCKS, 256, 0, stream>>>(row_start, csr_cv, h2b4, ybf4,
                                                 feats, h1b4, h2b4);

    // GEMM1 (MFMA): hid = relu(0.25*(ybf @ W1) + b1)
    dim3 g1((N_NODES + 63) / 64, 2);          // (782, 2)
    gemm1_mfma<<<g1, 256, 0, stream>>>(ybf4, W1frag, b1, hid);

    // GEMM2 (K-split x2): partials into dead y region
    dim3 g2((N_NODES + G2_BM - 1) / G2_BM, 2);        // (391, 2)
    gemm2_kernel<<<g2, 256, 0, stream>>>(hid, W2, part0, part1);

    // double log_softmax (sums partials + bias) -> out
    lsm_kernel<<<(N_NODES + 3) / 4, 256, 0, stream>>>(part0, part1, b2, out);
}